// Round 2
// baseline (241.551 us; speedup 1.0000x reference)
//
#include <hip/hip_runtime.h>
#include <stdint.h>

#define NB 32768
#define NPASS 4
#define FULL27 0x07FFFFFFu
#define NBF (NB * 729)            // 23,887,872 floats (= NB*729)
#define NWORDS (NBF / 32)         // 746,496 packed dwords (exact)
#define PACK_BLKS (NWORDS / 256)  // 2916 blocks (exact)
#define SOLVE_PPB 64              // puzzles per solve block (1 per lane)
#define SOLVE_BLKS (NB / SOLVE_PPB) // 512 blocks
#define BLK_DW 1458               // 64*729/32 dwords of packed bits per solve block (exact)

// Per-band bitboard: digit d, band b (rows 3b..3b+2), bit (r*9+c).
// BOX k mask within band: 0x1C0E07 << 3k ; COL c: 0x40201 << c ; ROW r: 0x1FF << 9r
// Flat float layout: puzzle p, digit d, band b, cell j == p*729 + d*81 + b*27 + j.
// Packed layout (ws): continuous bitstream, dword g holds floats [32g, 32g+32).
//
// SESSION LEDGER:
//   r15 (prev best 216.5us): 3 lanes/puzzle, ds_bpermute shuffles. kernel 107us.
//   r16 (213.5us): 4-lane quads + DPP quad_perm. LDS_CONF 3.0M->192K, VALUBusy
//     42->55, but only -3.5us: solve now issue-bound, pack latency-bound at
//     8 waves/CU (grid-capped). Single-kernel shape is the constraint.
//   r17 (this): phase-split. pack kernel = 2916x256, 8x dwordx4 aligned loads
//     -> exponent-bit pack -> 1 dw store; read-roofline (~16us predicted).
//     solve kernel = 512x64, 1 lane = 1 puzzle (27 band-words in regs), zero
//     cross-lane ops, shared symmetric cross-band terms (1x not 3x), LDS
//     staging for static reg indexing, fused expand (write roofline).

__device__ __forceinline__ uint32_t colfold(uint32_t w) {
    return (w | (w >> 9) | (w >> 18)) & 0x1FFu;
}
__device__ __forceinline__ uint32_t colmaj2(uint32_t w) {   // columns with >=2 bits in band
    return ((w & (w >> 9)) | ((w | (w >> 9)) & (w >> 18))) & 0x1FFu;
}

// ---------------------------------------------------------------------------
// PACK: float mask -> bitstream. Thread g packs floats [32g, 32g+32) -> ws[g].
// ---------------------------------------------------------------------------
__global__ __launch_bounds__(256)
void pack_kernel(const uint32_t* __restrict__ in, uint32_t* __restrict__ ws) {
    const int g = blockIdx.x * 256 + threadIdx.x;          // < 746,496 (grid exact)
    const uint4* src = (const uint4*)in + (size_t)g * 8;   // byte addr 128*g: aligned
    uint32_t acc = 0u;
    #pragma unroll
    for (int j = 0; j < 8; ++j) {
        uint4 v = src[j];
        // inputs are exactly 0.0f / 1.0f -> bit 23 of the pattern is the flag
        uint32_t n = ((v.x >> 23) & 1u) | (((v.y >> 23) & 1u) << 1)
                   | (((v.z >> 23) & 1u) << 2) | (((v.w >> 23) & 1u) << 3);
        acc |= n << (4 * j);
    }
    ws[g] = acc;
}

// ---------------------------------------------------------------------------
// SOLVE + EXPAND: one lane = one puzzle. 64 puzzles/block = 1458 packed dwords
// staged in LDS (block bit-range is dword-aligned: 64*729 = 46656 = 0 mod 32).
// ---------------------------------------------------------------------------
__global__ __launch_bounds__(64, 1)
void solve_kernel(const uint32_t* __restrict__ ws, float* __restrict__ out,
                  float* __restrict__ solved) {
    __shared__ uint32_t lds[BLK_DW + 1];
    const int lane = threadIdx.x;
    const int P0 = blockIdx.x * SOLVE_PPB;

    // ---- stage packed bits: 729 uint2 loads (8B aligned: block base = 5832B*blk)
    {
        const uint2* wsrc = (const uint2*)(ws + (size_t)blockIdx.x * BLK_DW);
        uint2* ldst = (uint2*)lds;
        #pragma unroll
        for (int i = 0; i < 12; ++i) {
            int j = i * 64 + lane;
            if (j < 729) ldst[j] = wsrc[j];
        }
    }
    __syncthreads();

    // ---- extract 27 band-words (runtime LDS index, static register index)
    uint32_t bd[9][3];
    {
        const int qb = lane * 729;
        #pragma unroll
        for (int d = 0; d < 9; ++d)
            #pragma unroll
            for (int b = 0; b < 3; ++b) {
                int bit = qb + d * 81 + b * 27;
                int di = bit >> 5, sh = bit & 31;
                uint64_t both = (uint64_t)lds[di] | ((uint64_t)lds[di + 1] << 32);
                bd[d][b] = (uint32_t)(both >> sh) & FULL27;
            }
    }

    // ---- solve (r16-validated logic; bands now in-lane, cross-band terms shared)
    #pragma unroll 1
    for (int pass = 0; pass < NPASS; ++pass) {
        // ---------- filter 'box' (band-local) ----------
        #pragma unroll
        for (int b = 0; b < 3; ++b) {
            uint32_t on = 0, tw = 0, fo = 0;
            #pragma unroll
            for (int d = 0; d < 9; ++d) {
                uint32_t c = on & bd[d][b];
                on ^= bd[d][b]; fo |= tw & c; tw ^= c;
            }
            uint32_t ex1 = on & ~tw & ~fo;
            #pragma unroll
            for (int d = 0; d < 9; ++d) {
                uint32_t s = bd[d][b] & ex1;
                #pragma unroll
                for (int k = 0; k < 3; ++k) {
                    uint32_t bm = 0x1C0E07u << (3 * k);
                    uint32_t sm = s & bm;
                    uint32_t multi = sm & (sm - 1u);
                    uint32_t keep = (sm == 0u) ? 0xFFFFFFFFu : (~bm | (multi ? 0u : sm));
                    bd[d][b] &= keep;
                }
            }
        }

        // ---------- pointing 'h' (band-local) ----------
        #pragma unroll
        for (int b = 0; b < 3; ++b)
            #pragma unroll
            for (int d = 0; d < 9; ++d) {
                uint32_t w = bd[d][b];
                uint32_t t = (w | (w >> 1) | (w >> 2)) & 0x01249249u;
                uint32_t sum = (t & 0x1FFu) + ((t >> 9) & 0x1FFu) + ((t >> 18) & 0x1FFu);
                uint32_t single = sum & ~(sum >> 1) & 0x49u;
                uint32_t point = t & (single * 0x40201u);
                uint32_t clearm = 0;
                #pragma unroll
                for (int r = 0; r < 3; ++r) {
                    uint32_t pr = (point >> (9 * r)) & 0x1FFu;
                    uint32_t multi = pr & (pr - 1u);
                    uint32_t segkeep = multi ? 0u : pr * 7u;
                    uint32_t rc = pr ? ((0x1FFu & ~segkeep) << (9 * r)) : 0u;
                    clearm |= rc;
                }
                bd[d][b] = w & ~clearm;
            }

        // ---------- pointing 'v' (cross-band, in-lane) ----------
        #pragma unroll
        for (int d = 0; d < 9; ++d) {
            uint32_t pn[3];
            #pragma unroll
            for (int b = 0; b < 3; ++b) {
                uint32_t w = bd[d][b];
                uint32_t q = colfold(w);
                uint32_t u = (q & 0x49u) + ((q >> 1) & 0x49u) + ((q >> 2) & 0x49u);
                uint32_t single = u & ~(u >> 1) & 0x49u;
                pn[b] = q & (single * 7u);
            }
            #pragma unroll
            for (int b = 0; b < 3; ++b) {
                uint32_t o = pn[(b + 1) % 3] | pn[(b + 2) % 3];
                bd[d][b] &= ~(o * 0x40201u);
            }
        }

        // ---------- unique 'h' (band-local) ----------
        #pragma unroll
        for (int b = 0; b < 3; ++b) {
            uint32_t hid[9], has = 0;
            #pragma unroll
            for (int d = 0; d < 9; ++d) {
                uint32_t w = bd[d][b], h = 0;
                #pragma unroll
                for (int r = 0; r < 3; ++r) {
                    uint32_t x = w & (0x1FFu << (9 * r));
                    h |= (x & (x - 1u)) ? 0u : x;
                }
                hid[d] = h; has |= h;
            }
            #pragma unroll
            for (int d = 0; d < 9; ++d) bd[d][b] = (bd[d][b] & ~has) | hid[d];
        }

        // ---------- unique 'v' (cross-band; symmetric terms computed once) ----------
        {
            uint32_t hid[9][3], has[3] = {0u, 0u, 0u};
            #pragma unroll
            for (int d = 0; d < 9; ++d) {
                uint32_t q[3], m[3];
                #pragma unroll
                for (int b = 0; b < 3; ++b) {
                    q[b] = colfold(bd[d][b]);
                    m[b] = colmaj2(bd[d][b]);
                }
                uint32_t ge2 = m[0] | m[1] | m[2]
                             | (q[0] & q[1]) | (q[0] & q[2]) | (q[1] & q[2]);
                uint32_t ex1c = (q[0] | q[1] | q[2]) & ~ge2;  // column count == 1
                #pragma unroll
                for (int b = 0; b < 3; ++b) {
                    hid[d][b] = bd[d][b] & ((ex1c & q[b]) * 0x40201u);
                    has[b] |= hid[d][b];
                }
            }
            #pragma unroll
            for (int d = 0; d < 9; ++d)
                #pragma unroll
                for (int b = 0; b < 3; ++b)
                    bd[d][b] = (bd[d][b] & ~has[b]) | hid[d][b];
        }

        // ---------- unique 'box' (band-local) ----------
        #pragma unroll
        for (int b = 0; b < 3; ++b) {
            uint32_t hid[9], has = 0;
            #pragma unroll
            for (int d = 0; d < 9; ++d) {
                uint32_t w = bd[d][b], h = 0;
                #pragma unroll
                for (int k = 0; k < 3; ++k) {
                    uint32_t x = w & (0x1C0E07u << (3 * k));
                    h |= (x & (x - 1u)) ? 0u : x;
                }
                hid[d] = h; has |= h;
            }
            #pragma unroll
            for (int d = 0; d < 9; ++d) bd[d][b] = (bd[d][b] & ~has) | hid[d];
        }

        // ---------- doubles 'v' twice (cross-band; dup/cols computed once) ----------
        #pragma unroll 1
        for (int rep = 0; rep < 2; ++rep) {
            uint32_t ex2[3];
            #pragma unroll
            for (int b = 0; b < 3; ++b) {
                uint32_t on = 0, tw = 0, fo = 0;
                #pragma unroll
                for (int d = 0; d < 9; ++d) {
                    uint32_t c = on & bd[d][b];
                    on ^= bd[d][b]; fo |= tw & c; tw ^= c;
                }
                ex2[b] = tw & ~on & ~fo;
            }
            uint32_t Q[9][3], K[9][3];
            #pragma unroll
            for (int d = 0; d < 9; ++d)
                #pragma unroll
                for (int b = 0; b < 3; ++b) { Q[d][b] = bd[d][b] & ex2[b]; K[d][b] = 0u; }
            #pragma unroll
            for (int d1 = 0; d1 < 9; ++d1)
                #pragma unroll
                for (int d2 = d1 + 1; d2 < 9; ++d2) {
                    uint32_t P[3], f[3], g[3];
                    #pragma unroll
                    for (int b = 0; b < 3; ++b) {
                        P[b] = Q[d1][b] & Q[d2][b];
                        f[b] = colfold(P[b]);
                        g[b] = colmaj2(P[b]);
                    }
                    // columns with >=2 exact-pair cells across the full column
                    uint32_t dup = g[0] | g[1] | g[2]
                                 | (f[0] & f[1]) | (f[0] & f[2]) | (f[1] & f[2]);
                    uint32_t em = dup * 0x40201u;
                    #pragma unroll
                    for (int b = 0; b < 3; ++b) {
                        uint32_t sK = P[b] & em;
                        K[d1][b] |= sK; K[d2][b] |= sK;
                    }
                }
            #pragma unroll
            for (int d = 0; d < 9; ++d) {
                uint32_t kc0 = colfold(K[d][0]), kc1 = colfold(K[d][1]), kc2 = colfold(K[d][2]);
                uint32_t em = (kc0 | kc1 | kc2) * 0x40201u;
                #pragma unroll
                for (int b = 0; b < 3; ++b)
                    bd[d][b] = (bd[d][b] & ~em) | K[d][b];
            }
        }

        // ---------- doubles 'box' (band-local) ----------
        #pragma unroll
        for (int b = 0; b < 3; ++b) {
            uint32_t on = 0, tw = 0, fo = 0;
            #pragma unroll
            for (int d = 0; d < 9; ++d) {
                uint32_t c = on & bd[d][b];
                on ^= bd[d][b]; fo |= tw & c; tw ^= c;
            }
            uint32_t ex2 = tw & ~on & ~fo;
            uint32_t Q[9], K[9];
            #pragma unroll
            for (int d = 0; d < 9; ++d) { Q[d] = bd[d][b] & ex2; K[d] = 0u; }
            #pragma unroll
            for (int d1 = 0; d1 < 9; ++d1)
                #pragma unroll
                for (int d2 = d1 + 1; d2 < 9; ++d2) {
                    uint32_t P = Q[d1] & Q[d2];
                    #pragma unroll
                    for (int k = 0; k < 3; ++k) {
                        uint32_t m = P & (0x1C0E07u << (3 * k));
                        uint32_t s = (m & (m - 1u)) ? m : 0u;
                        K[d1] |= s; K[d2] |= s;
                    }
                }
            #pragma unroll
            for (int d = 0; d < 9; ++d)
                #pragma unroll
                for (int k = 0; k < 3; ++k) {
                    uint32_t bm = 0x1C0E07u << (3 * k);
                    uint32_t t = K[d] & bm;
                    uint32_t mask = t ? (~bm | t) : 0xFFFFFFFFu;
                    bd[d][b] &= mask;
                }
        }
    } // passes

    // ---- solved flag (all in-lane now) ----
    {
        uint32_t ok = 1u;
        #pragma unroll
        for (int b = 0; b < 3; ++b) {
            uint32_t on = 0, tw = 0, fo = 0;
            #pragma unroll
            for (int d = 0; d < 9; ++d) {
                uint32_t c = on & bd[d][b];
                on ^= bd[d][b]; fo |= tw & c; tw ^= c;
            }
            ok &= ((on & ~tw & ~fo) == FULL27) ? 1u : 0u;
        }
        solved[P0 + lane] = ok ? 1.0f : 0.0f;
    }

    // ---- EXPAND: repack into LDS bitstream, then coalesced float4 stores ----
    __syncthreads();                          // staging reads fully consumed
    for (int j = lane; j < BLK_DW + 1; j += 64) lds[j] = 0u;
    __syncthreads();
    {
        const int qb = lane * 729;
        #pragma unroll
        for (int d = 0; d < 9; ++d)
            #pragma unroll
            for (int b = 0; b < 3; ++b) {
                int bit = qb + d * 81 + b * 27;
                int di = bit >> 5, sh = bit & 31;
                uint64_t both = (uint64_t)bd[d][b] << sh;
                atomicOr(&lds[di], (uint32_t)both);
                atomicOr(&lds[di + 1], (uint32_t)(both >> 32));
            }
    }
    __syncthreads();
    {
        float4* dst4 = (float4*)(out + (size_t)P0 * 729);  // 46656*blk floats: aligned
        #pragma unroll 4
        for (int i = 0; i < 183; ++i) {                    // 11664 float4s / 64 lanes
            int j = i * 64 + lane;
            if (j < 11664) {
                uint32_t nib = (lds[j >> 3] >> ((j & 7) * 4)) & 0xFu;
                dst4[j] = make_float4((float)(nib & 1u), (float)((nib >> 1) & 1u),
                                      (float)((nib >> 2) & 1u), (float)((nib >> 3) & 1u));
            }
        }
    }
}

extern "C" void kernel_launch(void* const* d_in, const int* in_sizes, int n_in,
                              void* d_out, int out_size, void* d_ws, size_t ws_size,
                              hipStream_t stream) {
    const uint32_t* in = (const uint32_t*)d_in[0];   // float32 bits; 0.0f / 1.0f
    float* out = (float*)d_out;
    float* solved = out + (size_t)NB * 729;
    uint32_t* ws = (uint32_t*)d_ws;                  // 746,496 dwords = 2.98 MB

    pack_kernel<<<PACK_BLKS, 256, 0, stream>>>(in, ws);
    solve_kernel<<<SOLVE_BLKS, 64, 0, stream>>>(ws, out, solved);
}

// Round 5
// 216.217 us; speedup vs baseline: 1.1172x; 1.1172x over previous
//
#include <hip/hip_runtime.h>
#include <stdint.h>

#define NB 32768
#define NPASS 4
#define FULL27 0x07FFFFFFu
#define NBF (NB * 729)            // 23,887,872 floats
#define NWORDS (NBF / 32)         // 746,496 packed dwords (exact)
#define PACK_BLKS (NWORDS / 256)  // 2916 blocks (exact)
#define PUZ_PER_BLK 64            // solve: 64 puzzles/block (16 per wave, 4 lanes each)
#define SOLVE_BLKS (NB / PUZ_PER_BLK)   // 512 blocks x 256 threads = 2048 waves
#define BLK_DW 1458               // 64*729/32 dwords of packed bits per block (exact)

// Per-band bitboard: digit d, band b (rows 3b..3b+2), bit (r*9+c).
// BOX k mask within band: 0x1C0E07 << 3k ; COL c: 0x40201 << c ; ROW r: 0x1FF << 9r
// Flat float layout: puzzle p, digit d, band b, cell j == p*729 + d*81 + b*27 + j.
// Packed ws layout: continuous bitstream, dword g holds floats [32g, 32g+32).
//
// SESSION LEDGER:
//   r15 (216.5us): 3 lanes/puzzle single kernel, ds_bpermute. kernel 107us.
//   r16 (213.5us): quad DPP bands. LDS_CONF 3.0M->192K, VALUBusy 42->55, only
//     -3.5us: pack latency-bound at 8 waves/CU, solve issue-bound. Phases
//     want different shapes.
//   r17 (241.6us REGRESSION): phase split, but solve at 1 lane=1 puzzle =
//     512 waves = 0.5 waves/SIMD -> half the SIMDs empty (VALUBusy 31%,
//     Occ 5.4%), solve alone 101us. Lesson: never drop below 1 wave/SIMD.
//     KEEPER: dedicated pack kernel runs ~roofline (~16us, vs ~40 in-wave).
//   r18: pack kernel (unchanged) + quad-DPP solve+expand kernel
//     (r16-validated solve logic, 2048 waves = 2/SIMD, reads packed ws via
//     aligned LDS stage). Predict solve ~65us, total kernels ~82us.
//   r19/r20 (this): identical resubmits — r18/r19 benches both died on
//     GPUAcquisitionTimeout (infra, no signal).

__device__ __forceinline__ uint32_t colfold(uint32_t w) {
    return (w | (w >> 9) | (w >> 18)) & 0x1FFu;
}
__device__ __forceinline__ uint32_t colmaj2(uint32_t w) {   // columns with >=2 bits in band
    return ((w & (w >> 9)) | ((w | (w >> 9)) & (w >> 18))) & 0x1FFu;
}
// quad_perm rotations within the 4-lane quad: band b reads band (b+1)%3 / (b-1)%3.
// ctrl = sel0 | sel1<<2 | sel2<<4 | sel3<<6 : [1,2,0,0]=0x09 ; [2,0,1,0]=0x12
__device__ __forceinline__ uint32_t rotA(uint32_t v) {      // from band+1 (mod 3)
    return (uint32_t)__builtin_amdgcn_update_dpp(0, (int)v, 0x09, 0xF, 0xF, true);
}
__device__ __forceinline__ uint32_t rotB(uint32_t v) {      // from band-1 (mod 3)
    return (uint32_t)__builtin_amdgcn_update_dpp(0, (int)v, 0x12, 0xF, 0xF, true);
}

// ---------------------------------------------------------------------------
// PACK: float mask -> bitstream. Thread g packs floats [32g, 32g+32) -> ws[g].
// 746,496 threads; 8x dwordx4 aligned loads each; read-roofline.
// ---------------------------------------------------------------------------
__global__ __launch_bounds__(256)
void pack_kernel(const uint32_t* __restrict__ in, uint32_t* __restrict__ ws) {
    const int g = blockIdx.x * 256 + threadIdx.x;          // < 746,496 (grid exact)
    const uint4* src = (const uint4*)in + (size_t)g * 8;   // byte addr 128*g: aligned
    uint32_t acc = 0u;
    #pragma unroll
    for (int j = 0; j < 8; ++j) {
        uint4 v = src[j];
        // inputs are exactly 0.0f / 1.0f -> bit 23 of the pattern is the flag
        uint32_t n = ((v.x >> 23) & 1u) | (((v.y >> 23) & 1u) << 1)
                   | (((v.z >> 23) & 1u) << 2) | (((v.w >> 23) & 1u) << 3);
        acc |= n << (4 * j);
    }
    ws[g] = acc;
}

// ---------------------------------------------------------------------------
// SOLVE + EXPAND: 4 lanes/puzzle (bands 0-2 live, 3 idle), 64 puzzles/block.
// Packed bits staged to LDS (block range = 1458 dw exact, uint2-aligned).
// ---------------------------------------------------------------------------
__global__ __launch_bounds__(256)
void solve_kernel(const uint32_t* __restrict__ ws, float* __restrict__ out,
                  float* __restrict__ solved) {
    __shared__ uint32_t lds[BLK_DW + 2];    // +2: band-3 lanes read 1 dw past range
    const int tid = threadIdx.x;
    const int q = tid >> 2;                 // puzzle slot 0..63
    const int band = tid & 3;               // 0..2 live, 3 idle in solve
    const int P0 = blockIdx.x * PUZ_PER_BLK;

    // ---- stage packed bits: 729 uint2 loads (block base = 5832B*blk: aligned)
    {
        const uint2* wsrc = (const uint2*)(ws + (size_t)blockIdx.x * BLK_DW);
        uint2* ldst = (uint2*)lds;
        #pragma unroll
        for (int i = 0; i < 3; ++i) {
            int j = i * 256 + tid;
            if (j < 729) ldst[j] = wsrc[j];
        }
    }
    __syncthreads();

    // ---- extract 9 band-words for this lane (band 3 reads in-bounds garbage)
    uint32_t bd[9];
    {
        const int bb0 = q * 729 + band * 27;
        #pragma unroll
        for (int d = 0; d < 9; ++d) {
            int bit = bb0 + d * 81;
            int di = bit >> 5, sh = bit & 31;
            uint64_t both = (uint64_t)lds[di] | ((uint64_t)lds[di + 1] << 32);
            bd[d] = (uint32_t)(both >> sh) & FULL27;
        }
    }
    __syncthreads();    // extraction done before pool reuse for expand

    // ---------------- SOLVE (r16-validated quad-DPP logic, unchanged) ----------
    #pragma unroll 1
    for (int pass = 0; pass < NPASS; ++pass) {
        // ---------- filter 'box' (band-local) ----------
        {
            uint32_t on = 0, tw = 0, fo = 0;
            #pragma unroll
            for (int d = 0; d < 9; ++d) {
                uint32_t c = on & bd[d];
                on ^= bd[d]; fo |= tw & c; tw ^= c;
            }
            uint32_t ex1 = on & ~tw & ~fo;
            #pragma unroll
            for (int d = 0; d < 9; ++d) {
                uint32_t s = bd[d] & ex1;
                #pragma unroll
                for (int k = 0; k < 3; ++k) {
                    uint32_t bm = 0x1C0E07u << (3 * k);
                    uint32_t sm = s & bm;
                    uint32_t multi = sm & (sm - 1u);
                    uint32_t keep = (sm == 0u) ? 0xFFFFFFFFu : (~bm | (multi ? 0u : sm));
                    bd[d] &= keep;
                }
            }
        }

        // ---------- pointing 'h' (band-local) ----------
        #pragma unroll
        for (int d = 0; d < 9; ++d) {
            uint32_t w = bd[d];
            uint32_t t = (w | (w >> 1) | (w >> 2)) & 0x01249249u;
            uint32_t sum = (t & 0x1FFu) + ((t >> 9) & 0x1FFu) + ((t >> 18) & 0x1FFu);
            uint32_t single = sum & ~(sum >> 1) & 0x49u;
            uint32_t point = t & (single * 0x40201u);
            uint32_t clearm = 0;
            #pragma unroll
            for (int r = 0; r < 3; ++r) {
                uint32_t pr = (point >> (9 * r)) & 0x1FFu;
                uint32_t multi = pr & (pr - 1u);
                uint32_t segkeep = multi ? 0u : pr * 7u;
                uint32_t rc = pr ? ((0x1FFu & ~segkeep) << (9 * r)) : 0u;
                clearm |= rc;
            }
            bd[d] = w & ~clearm;
        }

        // ---------- pointing 'v' (cross-band via DPP) ----------
        {
            uint32_t pnt[9];
            #pragma unroll
            for (int d = 0; d < 9; ++d) {
                uint32_t w = bd[d];
                uint32_t qq = colfold(w);
                uint32_t u = (qq & 0x49u) + ((qq >> 1) & 0x49u) + ((qq >> 2) & 0x49u);
                uint32_t single = u & ~(u >> 1) & 0x49u;
                pnt[d] = qq & (single * 7u);
            }
            #pragma unroll
            for (int d = 0; d < 9; ++d) {
                uint32_t o = rotA(pnt[d]) | rotB(pnt[d]);
                bd[d] &= ~(o * 0x40201u);
            }
        }

        // ---------- unique 'h' (band-local) ----------
        {
            uint32_t hid[9], has = 0;
            #pragma unroll
            for (int d = 0; d < 9; ++d) {
                uint32_t w = bd[d], h = 0;
                #pragma unroll
                for (int r = 0; r < 3; ++r) {
                    uint32_t x = w & (0x1FFu << (9 * r));
                    h |= (x & (x - 1u)) ? 0u : x;
                }
                hid[d] = h; has |= h;
            }
            #pragma unroll
            for (int d = 0; d < 9; ++d) bd[d] = (bd[d] & ~has) | hid[d];
        }

        // ---------- unique 'v' (cross-band via DPP) ----------
        {
            uint32_t hid[9], has = 0;
            #pragma unroll
            for (int d = 0; d < 9; ++d) {
                uint32_t w = bd[d];
                uint32_t q0 = colfold(w), m0 = colmaj2(w);
                uint32_t ex = q0 | (m0 << 9);
                uint32_t ea = rotA(ex);
                uint32_t eb = rotB(ex);
                uint32_t qa = ea & 0x1FFu, ma = ea >> 9;
                uint32_t qb = eb & 0x1FFu, mb = eb >> 9;
                uint32_t ge2 = m0 | ma | mb | (q0 & qa) | (q0 & qb) | (qa & qb);
                uint32_t ex1c = (q0 | qa | qb) & ~ge2;   // column total count == 1
                hid[d] = w & ((ex1c & q0) * 0x40201u);
                has |= hid[d];
            }
            #pragma unroll
            for (int d = 0; d < 9; ++d) bd[d] = (bd[d] & ~has) | hid[d];
        }

        // ---------- unique 'box' (band-local) ----------
        {
            uint32_t hid[9], has = 0;
            #pragma unroll
            for (int d = 0; d < 9; ++d) {
                uint32_t w = bd[d], h = 0;
                #pragma unroll
                for (int k = 0; k < 3; ++k) {
                    uint32_t x = w & (0x1C0E07u << (3 * k));
                    h |= (x & (x - 1u)) ? 0u : x;
                }
                hid[d] = h; has |= h;
            }
            #pragma unroll
            for (int d = 0; d < 9; ++d) bd[d] = (bd[d] & ~has) | hid[d];
        }

        // ---------- doubles 'v' twice (cross-band via DPP) ----------
        #pragma unroll 1
        for (int rep = 0; rep < 2; ++rep) {
            uint32_t on = 0, tw = 0, fo = 0;
            #pragma unroll
            for (int d = 0; d < 9; ++d) {
                uint32_t c = on & bd[d];
                on ^= bd[d]; fo |= tw & c; tw ^= c;
            }
            uint32_t ex2 = tw & ~on & ~fo;
            uint32_t Q[9], K[9];
            #pragma unroll
            for (int d = 0; d < 9; ++d) { Q[d] = bd[d] & ex2; K[d] = 0u; }
            #pragma unroll
            for (int d1 = 0; d1 < 9; ++d1)
                #pragma unroll
                for (int d2 = d1 + 1; d2 < 9; ++d2) {
                    uint32_t P = Q[d1] & Q[d2];
                    uint32_t f0 = colfold(P), g0 = colmaj2(P);
                    uint32_t ex = f0 | (g0 << 9);
                    uint32_t ea = rotA(ex);
                    uint32_t eb = rotB(ex);
                    uint32_t fa = ea & 0x1FFu, ga = ea >> 9;
                    uint32_t fb = eb & 0x1FFu, gb = eb >> 9;
                    // columns with >=2 exact-pair cells across the full column
                    uint32_t dup = g0 | ga | gb | (f0 & fa) | (f0 & fb) | (fa & fb);
                    uint32_t sK = P & (dup * 0x40201u);
                    K[d1] |= sK; K[d2] |= sK;
                }
            #pragma unroll
            for (int d = 0; d < 9; ++d) {
                uint32_t kc = colfold(K[d]);
                uint32_t cols = kc | rotA(kc) | rotB(kc);
                uint32_t em = cols * 0x40201u;
                bd[d] = (bd[d] & ~em) | K[d];
            }
        }

        // ---------- doubles 'box' (band-local) ----------
        {
            uint32_t on = 0, tw = 0, fo = 0;
            #pragma unroll
            for (int d = 0; d < 9; ++d) {
                uint32_t c = on & bd[d];
                on ^= bd[d]; fo |= tw & c; tw ^= c;
            }
            uint32_t ex2 = tw & ~on & ~fo;
            uint32_t Q[9], K[9];
            #pragma unroll
            for (int d = 0; d < 9; ++d) { Q[d] = bd[d] & ex2; K[d] = 0u; }
            #pragma unroll
            for (int d1 = 0; d1 < 9; ++d1)
                #pragma unroll
                for (int d2 = d1 + 1; d2 < 9; ++d2) {
                    uint32_t P = Q[d1] & Q[d2];
                    #pragma unroll
                    for (int k = 0; k < 3; ++k) {
                        uint32_t m = P & (0x1C0E07u << (3 * k));
                        uint32_t s = (m & (m - 1u)) ? m : 0u;
                        K[d1] |= s; K[d2] |= s;
                    }
                }
            #pragma unroll
            for (int d = 0; d < 9; ++d)
                #pragma unroll
                for (int k = 0; k < 3; ++k) {
                    uint32_t bm = 0x1C0E07u << (3 * k);
                    uint32_t t = K[d] & bm;
                    uint32_t mask = t ? (~bm | t) : 0xFFFFFFFFu;
                    bd[d] &= mask;
                }
        }
    } // passes

    // ---------------- solved flag (AND across quad via DPP) ----------------
    {
        uint32_t on = 0, tw = 0, fo = 0;
        #pragma unroll
        for (int d = 0; d < 9; ++d) {
            uint32_t c = on & bd[d];
            on ^= bd[d]; fo |= tw & c; tw ^= c;
        }
        uint32_t okb = ((on & ~tw & ~fo) == FULL27) ? 1u : 0u;
        uint32_t all = okb & rotA(okb) & rotB(okb);
        if (band == 0) solved[P0 + q] = all ? 1.0f : 0.0f;
    }

    // ---------------- EXPAND: repack to LDS bitstream -> float4 stores ---------
    for (int j = tid; j < BLK_DW + 2; j += 256) lds[j] = 0u;
    __syncthreads();
    if (band != 3) {
        const int pbit = q * 729;
        #pragma unroll
        for (int d = 0; d < 9; ++d) {
            int bitbase = pbit + d * 81 + band * 27;
            int di = bitbase >> 5;
            int sh = bitbase & 31;
            uint64_t both = (uint64_t)bd[d] << sh;
            atomicOr(&lds[di], (uint32_t)both);
            atomicOr(&lds[di + 1], (uint32_t)(both >> 32));
        }
    }
    __syncthreads();
    {
        float4* dst4 = (float4*)(out + (size_t)P0 * 729);  // 46656*blk floats: aligned
        #pragma unroll 4
        for (int i = 0; i < 46; ++i) {                     // 11664 float4s / 256 lanes
            int j = i * 256 + tid;
            if (j < 11664) {
                uint32_t nib = (lds[j >> 3] >> ((j & 7) * 4)) & 0xFu;
                dst4[j] = make_float4((float)(nib & 1u), (float)((nib >> 1) & 1u),
                                      (float)((nib >> 2) & 1u), (float)((nib >> 3) & 1u));
            }
        }
    }
}

extern "C" void kernel_launch(void* const* d_in, const int* in_sizes, int n_in,
                              void* d_out, int out_size, void* d_ws, size_t ws_size,
                              hipStream_t stream) {
    const uint32_t* in = (const uint32_t*)d_in[0];   // float32 bits; 0.0f / 1.0f
    float* out = (float*)d_out;
    float* solved = out + (size_t)NB * 729;
    uint32_t* ws = (uint32_t*)d_ws;                  // 746,496 dwords = 2.98 MB

    pack_kernel<<<PACK_BLKS, 256, 0, stream>>>(in, ws);
    solve_kernel<<<SOLVE_BLKS, 256, 0, stream>>>(ws, out, solved);
}

// Round 6
// 215.560 us; speedup vs baseline: 1.1206x; 1.0030x over previous
//
#include <hip/hip_runtime.h>
#include <stdint.h>

#define NB 32768
#define NPASS 4
#define FULL27 0x07FFFFFFu
#define PUZ_PER_BLK 64            // 64 puzzles/block (16 per wave, 4 lanes each)
#define SOLVE_BLKS (NB / PUZ_PER_BLK)   // 512 blocks x 256 threads = 2048 waves
#define BLK_DW 1458               // 64*729/32 dwords of bits per block (exact)
#define BLK_V4 11664              // 64*729/4 vec4 loads per block (exact)

// Per-band bitboard: digit d, band b (rows 3b..3b+2), bit (r*9+c).
// BOX k mask within band: 0x1C0E07 << 3k ; COL c: 0x40201 << c ; ROW r: 0x1FF << 9r
// Flat float layout: puzzle p, digit d, band b, cell j == p*729 + d*81 + b*27 + j.
// Pool layout: bit j of block pool == float blk*46656 + j.
//
// SESSION LEDGER:
//   r15 (216.5us): 3 lanes/puzzle single kernel, ds_bpermute. kernel 107us.
//   r16 (213.5us): quad DPP bands. LDS_CONF 3.0M->192K, VALUBusy 42->55, only
//     -3.5us: pack latency-bound, solve issue-bound. Phases want diff shapes.
//   r17 (241.6us REGRESSION): split, solve 1 lane=1 puzzle = 512 waves = 0.5
//     waves/SIMD -> VALUBusy 31%, solve 101us. Never drop below 1 wave/SIMD.
//   r18/r20 (216.2us): split pack (2916x256 private-chunk loads) + quad-DPP
//     solve (2048 waves). Solve 72us @ VALUBusy 73-75% (prediction matched).
//     BUT pack+gap ~34us vs 16us roofline: private 128B chunks -> 64 distinct
//     lines per VMEM instr (8x request inflation) + kernel-gap. Net flat.
//   r21 (this): single kernel again. Pack fused into solve with COALESCED
//     loads (lane-contiguous vec4) -> nibble (exp-bit) -> quad_perm DPP tree
//     (xor1,xor2) -> paired ds_write_b16 into pool. No ballot, no lane0
//     serialization, no ws, no gap. Predict kernel ~87us, total ~199us.

__device__ __forceinline__ uint32_t colfold(uint32_t w) {
    return (w | (w >> 9) | (w >> 18)) & 0x1FFu;
}
__device__ __forceinline__ uint32_t colmaj2(uint32_t w) {   // columns with >=2 bits in band
    return ((w & (w >> 9)) | ((w | (w >> 9)) & (w >> 18))) & 0x1FFu;
}
// quad_perm rotations within the 4-lane quad: band b reads band (b+1)%3 / (b-1)%3.
// ctrl = sel0 | sel1<<2 | sel2<<4 | sel3<<6 : [1,2,0,0]=0x09 ; [2,0,1,0]=0x12
__device__ __forceinline__ uint32_t rotA(uint32_t v) {      // from band+1 (mod 3)
    return (uint32_t)__builtin_amdgcn_update_dpp(0, (int)v, 0x09, 0xF, 0xF, true);
}
__device__ __forceinline__ uint32_t rotB(uint32_t v) {      // from band-1 (mod 3)
    return (uint32_t)__builtin_amdgcn_update_dpp(0, (int)v, 0x12, 0xF, 0xF, true);
}
// pack-tree swaps: quad_perm [1,0,3,2]=0xB1 (lane^1), [2,3,0,1]=0x4E (lane^2)
__device__ __forceinline__ uint32_t dppx1(uint32_t v) {
    return (uint32_t)__builtin_amdgcn_update_dpp(0, (int)v, 0xB1, 0xF, 0xF, true);
}
__device__ __forceinline__ uint32_t dppx2(uint32_t v) {
    return (uint32_t)__builtin_amdgcn_update_dpp(0, (int)v, 0x4E, 0xF, 0xF, true);
}

__global__ __launch_bounds__(256)
void sudoku_kernel(const uint32_t* __restrict__ in, float* __restrict__ out,
                   float* __restrict__ solved) {
    __shared__ uint32_t pool[BLK_DW + 2];   // 46656 bits (+pad for extract's 64b read)
    const int tid = threadIdx.x;
    const int q = tid >> 2;                 // puzzle slot 0..63
    const int band = tid & 3;               // 0..2 live, 3 idle in solve
    const int P0 = blockIdx.x * PUZ_PER_BLK;

    // ---------------- PACK (fused, coalesced): floats -> pool bitstream -------
    // iter it: lane loads vec4 index it*256+tid (wave = 256 contiguous floats).
    // Lane l=8k+m holds floats [32D+4m, 32D+4m+4), D = it*32 + tid/8.
    // DPP xor1: byte on m-even; DPP xor2: u16 on m%4==0; lanes m=0/4 write
    // the low/high halves of pool[D] via ds_write_b16 (same bank, 2-way free).
    {
        const uint4* src = (const uint4*)in + (size_t)blockIdx.x * BLK_V4;
        uint16_t* hp = (uint16_t*)pool;
        #pragma unroll 1
        for (int ii = 0; ii < 6; ++ii) {            // 6 chunks x 8 iters = 48 (>=46)
            uint4 v[8];
            #pragma unroll
            for (int j = 0; j < 8; ++j) {
                int vi = (ii * 8 + j) * 256 + tid;
                if (vi > BLK_V4 - 1) vi = BLK_V4 - 1;   // clamp (write masked below)
                v[j] = src[vi];
            }
            #pragma unroll
            for (int j = 0; j < 8; ++j) {
                int it = ii * 8 + j;
                // inputs are exactly 0.0f/1.0f -> bit 23 of the pattern is the flag
                uint32_t n = ((v[j].x >> 23) & 1u) | ((v[j].y >> 22) & 2u)
                           | ((v[j].z >> 21) & 4u) | ((v[j].w >> 20) & 8u);
                uint32_t b = n | (dppx1(n) << 4);       // byte, valid on even lanes
                uint32_t h = b | (dppx2(b) << 8);       // u16, valid on lane%4==0
                if ((tid & 3) == 0) {
                    int D = it * 32 + (tid >> 3);
                    if (D < BLK_DW)
                        hp[2 * D + ((tid >> 2) & 1)] = (uint16_t)h;
                }
            }
        }
    }
    __syncthreads();

    // ---- extract 9 band-words for this lane (band 3 reads in-bounds garbage)
    uint32_t bd[9];
    {
        const int bb0 = q * 729 + band * 27;
        #pragma unroll
        for (int d = 0; d < 9; ++d) {
            int bit = bb0 + d * 81;
            int di = bit >> 5, sh = bit & 31;
            uint64_t both = (uint64_t)pool[di] | ((uint64_t)pool[di + 1] << 32);
            bd[d] = (uint32_t)(both >> sh) & FULL27;
        }
    }
    __syncthreads();    // extraction done before pool reuse for expand

    // ---------------- SOLVE (r16/r20-validated quad-DPP logic, unchanged) ------
    #pragma unroll 1
    for (int pass = 0; pass < NPASS; ++pass) {
        // ---------- filter 'box' (band-local) ----------
        {
            uint32_t on = 0, tw = 0, fo = 0;
            #pragma unroll
            for (int d = 0; d < 9; ++d) {
                uint32_t c = on & bd[d];
                on ^= bd[d]; fo |= tw & c; tw ^= c;
            }
            uint32_t ex1 = on & ~tw & ~fo;
            #pragma unroll
            for (int d = 0; d < 9; ++d) {
                uint32_t s = bd[d] & ex1;
                #pragma unroll
                for (int k = 0; k < 3; ++k) {
                    uint32_t bm = 0x1C0E07u << (3 * k);
                    uint32_t sm = s & bm;
                    uint32_t multi = sm & (sm - 1u);
                    uint32_t keep = (sm == 0u) ? 0xFFFFFFFFu : (~bm | (multi ? 0u : sm));
                    bd[d] &= keep;
                }
            }
        }

        // ---------- pointing 'h' (band-local) ----------
        #pragma unroll
        for (int d = 0; d < 9; ++d) {
            uint32_t w = bd[d];
            uint32_t t = (w | (w >> 1) | (w >> 2)) & 0x01249249u;
            uint32_t sum = (t & 0x1FFu) + ((t >> 9) & 0x1FFu) + ((t >> 18) & 0x1FFu);
            uint32_t single = sum & ~(sum >> 1) & 0x49u;
            uint32_t point = t & (single * 0x40201u);
            uint32_t clearm = 0;
            #pragma unroll
            for (int r = 0; r < 3; ++r) {
                uint32_t pr = (point >> (9 * r)) & 0x1FFu;
                uint32_t multi = pr & (pr - 1u);
                uint32_t segkeep = multi ? 0u : pr * 7u;
                uint32_t rc = pr ? ((0x1FFu & ~segkeep) << (9 * r)) : 0u;
                clearm |= rc;
            }
            bd[d] = w & ~clearm;
        }

        // ---------- pointing 'v' (cross-band via DPP) ----------
        {
            uint32_t pnt[9];
            #pragma unroll
            for (int d = 0; d < 9; ++d) {
                uint32_t w = bd[d];
                uint32_t qq = colfold(w);
                uint32_t u = (qq & 0x49u) + ((qq >> 1) & 0x49u) + ((qq >> 2) & 0x49u);
                uint32_t single = u & ~(u >> 1) & 0x49u;
                pnt[d] = qq & (single * 7u);
            }
            #pragma unroll
            for (int d = 0; d < 9; ++d) {
                uint32_t o = rotA(pnt[d]) | rotB(pnt[d]);
                bd[d] &= ~(o * 0x40201u);
            }
        }

        // ---------- unique 'h' (band-local) ----------
        {
            uint32_t hid[9], has = 0;
            #pragma unroll
            for (int d = 0; d < 9; ++d) {
                uint32_t w = bd[d], h = 0;
                #pragma unroll
                for (int r = 0; r < 3; ++r) {
                    uint32_t x = w & (0x1FFu << (9 * r));
                    h |= (x & (x - 1u)) ? 0u : x;
                }
                hid[d] = h; has |= h;
            }
            #pragma unroll
            for (int d = 0; d < 9; ++d) bd[d] = (bd[d] & ~has) | hid[d];
        }

        // ---------- unique 'v' (cross-band via DPP) ----------
        {
            uint32_t hid[9], has = 0;
            #pragma unroll
            for (int d = 0; d < 9; ++d) {
                uint32_t w = bd[d];
                uint32_t q0 = colfold(w), m0 = colmaj2(w);
                uint32_t ex = q0 | (m0 << 9);
                uint32_t ea = rotA(ex);
                uint32_t eb = rotB(ex);
                uint32_t qa = ea & 0x1FFu, ma = ea >> 9;
                uint32_t qb = eb & 0x1FFu, mb = eb >> 9;
                uint32_t ge2 = m0 | ma | mb | (q0 & qa) | (q0 & qb) | (qa & qb);
                uint32_t ex1c = (q0 | qa | qb) & ~ge2;   // column total count == 1
                hid[d] = w & ((ex1c & q0) * 0x40201u);
                has |= hid[d];
            }
            #pragma unroll
            for (int d = 0; d < 9; ++d) bd[d] = (bd[d] & ~has) | hid[d];
        }

        // ---------- unique 'box' (band-local) ----------
        {
            uint32_t hid[9], has = 0;
            #pragma unroll
            for (int d = 0; d < 9; ++d) {
                uint32_t w = bd[d], h = 0;
                #pragma unroll
                for (int k = 0; k < 3; ++k) {
                    uint32_t x = w & (0x1C0E07u << (3 * k));
                    h |= (x & (x - 1u)) ? 0u : x;
                }
                hid[d] = h; has |= h;
            }
            #pragma unroll
            for (int d = 0; d < 9; ++d) bd[d] = (bd[d] & ~has) | hid[d];
        }

        // ---------- doubles 'v' twice (cross-band via DPP) ----------
        #pragma unroll 1
        for (int rep = 0; rep < 2; ++rep) {
            uint32_t on = 0, tw = 0, fo = 0;
            #pragma unroll
            for (int d = 0; d < 9; ++d) {
                uint32_t c = on & bd[d];
                on ^= bd[d]; fo |= tw & c; tw ^= c;
            }
            uint32_t ex2 = tw & ~on & ~fo;
            uint32_t Q[9], K[9];
            #pragma unroll
            for (int d = 0; d < 9; ++d) { Q[d] = bd[d] & ex2; K[d] = 0u; }
            #pragma unroll
            for (int d1 = 0; d1 < 9; ++d1)
                #pragma unroll
                for (int d2 = d1 + 1; d2 < 9; ++d2) {
                    uint32_t P = Q[d1] & Q[d2];
                    uint32_t f0 = colfold(P), g0 = colmaj2(P);
                    uint32_t ex = f0 | (g0 << 9);
                    uint32_t ea = rotA(ex);
                    uint32_t eb = rotB(ex);
                    uint32_t fa = ea & 0x1FFu, ga = ea >> 9;
                    uint32_t fb = eb & 0x1FFu, gb = eb >> 9;
                    // columns with >=2 exact-pair cells across the full column
                    uint32_t dup = g0 | ga | gb | (f0 & fa) | (f0 & fb) | (fa & fb);
                    uint32_t sK = P & (dup * 0x40201u);
                    K[d1] |= sK; K[d2] |= sK;
                }
            #pragma unroll
            for (int d = 0; d < 9; ++d) {
                uint32_t kc = colfold(K[d]);
                uint32_t cols = kc | rotA(kc) | rotB(kc);
                uint32_t em = cols * 0x40201u;
                bd[d] = (bd[d] & ~em) | K[d];
            }
        }

        // ---------- doubles 'box' (band-local) ----------
        {
            uint32_t on = 0, tw = 0, fo = 0;
            #pragma unroll
            for (int d = 0; d < 9; ++d) {
                uint32_t c = on & bd[d];
                on ^= bd[d]; fo |= tw & c; tw ^= c;
            }
            uint32_t ex2 = tw & ~on & ~fo;
            uint32_t Q[9], K[9];
            #pragma unroll
            for (int d = 0; d < 9; ++d) { Q[d] = bd[d] & ex2; K[d] = 0u; }
            #pragma unroll
            for (int d1 = 0; d1 < 9; ++d1)
                #pragma unroll
                for (int d2 = d1 + 1; d2 < 9; ++d2) {
                    uint32_t P = Q[d1] & Q[d2];
                    #pragma unroll
                    for (int k = 0; k < 3; ++k) {
                        uint32_t m = P & (0x1C0E07u << (3 * k));
                        uint32_t s = (m & (m - 1u)) ? m : 0u;
                        K[d1] |= s; K[d2] |= s;
                    }
                }
            #pragma unroll
            for (int d = 0; d < 9; ++d)
                #pragma unroll
                for (int k = 0; k < 3; ++k) {
                    uint32_t bm = 0x1C0E07u << (3 * k);
                    uint32_t t = K[d] & bm;
                    uint32_t mask = t ? (~bm | t) : 0xFFFFFFFFu;
                    bd[d] &= mask;
                }
        }
    } // passes

    // ---------------- solved flag (AND across quad via DPP) ----------------
    {
        uint32_t on = 0, tw = 0, fo = 0;
        #pragma unroll
        for (int d = 0; d < 9; ++d) {
            uint32_t c = on & bd[d];
            on ^= bd[d]; fo |= tw & c; tw ^= c;
        }
        uint32_t okb = ((on & ~tw & ~fo) == FULL27) ? 1u : 0u;
        uint32_t all = okb & rotA(okb) & rotB(okb);
        if (band == 0) solved[P0 + q] = all ? 1.0f : 0.0f;
    }

    // ---------------- EXPAND: repack to pool bitstream -> float4 stores --------
    for (int j = tid; j < BLK_DW + 2; j += 256) pool[j] = 0u;
    __syncthreads();
    if (band != 3) {
        const int pbit = q * 729;
        #pragma unroll
        for (int d = 0; d < 9; ++d) {
            int bitbase = pbit + d * 81 + band * 27;
            int di = bitbase >> 5;
            int sh = bitbase & 31;
            uint64_t both = (uint64_t)bd[d] << sh;
            atomicOr(&pool[di], (uint32_t)both);
            atomicOr(&pool[di + 1], (uint32_t)(both >> 32));
        }
    }
    __syncthreads();
    {
        float4* dst4 = (float4*)(out + (size_t)P0 * 729);  // 46656*blk floats: aligned
        #pragma unroll 4
        for (int i = 0; i < 46; ++i) {                     // 11664 float4s / 256 lanes
            int j = i * 256 + tid;
            if (j < 11664) {
                uint32_t nib = (pool[j >> 3] >> ((j & 7) * 4)) & 0xFu;
                dst4[j] = make_float4((float)(nib & 1u), (float)((nib >> 1) & 1u),
                                      (float)((nib >> 2) & 1u), (float)((nib >> 3) & 1u));
            }
        }
    }
}

extern "C" void kernel_launch(void* const* d_in, const int* in_sizes, int n_in,
                              void* d_out, int out_size, void* d_ws, size_t ws_size,
                              hipStream_t stream) {
    const uint32_t* in = (const uint32_t*)d_in[0];   // float32 bits; 0.0f / 1.0f
    float* out = (float*)d_out;
    float* solved = out + (size_t)NB * 729;
    // single kernel: 512 blocks x 256 threads (2 blocks/CU, 8 waves/CU)
    sudoku_kernel<<<SOLVE_BLKS, 256, 0, stream>>>(in, out, solved);
}

// Round 7
// 209.665 us; speedup vs baseline: 1.1521x; 1.0281x over previous
//
#include <hip/hip_runtime.h>
#include <stdint.h>

#define NB 32768
#define NPASS 4
#define FULL27 0x07FFFFFFu
#define PUZ_PER_BLK 64            // 64 puzzles/block (16 per wave, 4 lanes each)
#define SOLVE_BLKS (NB / PUZ_PER_BLK)   // 512 blocks x 256 threads = 2048 waves
#define BLK_DW 1458               // 64*729/32 dwords of bits per block (exact)
#define BLK_V4 11664              // 64*729/4 vec4 loads per block (exact)

// Per-band bitboard: digit d, band b (rows 3b..3b+2), bit (r*9+c).
// BOX k mask within band: 0x1C0E07 << 3k ; COL c: 0x40201 << c ; ROW r: 0x1FF << 9r
// Flat float layout: puzzle p, digit d, band b, cell j == p*729 + d*81 + b*27 + j.
// Pool layout: bit j of block pool == float blk*46656 + j.
//
// SESSION LEDGER:
//   r15 (216.5us): 3 lanes/puzzle single kernel, ds_bpermute. kernel 107us.
//   r16 (213.5us): quad DPP bands. LDS_CONF 3.0M->192K, VALUBusy 42->55.
//   r17 (241.6us REGRESSION): split, solve 1 lane=1 puzzle = 512 waves -> half
//     the SIMDs empty. Never drop below 1 wave/SIMD.
//   r18/r20 (216.2us): split. Solve 72us @ VALUBusy 73-75% (matched). Pack+gap
//     ~34us vs 16 roofline (private-chunk line inflation).
//   r21 (215.6us): fused coalesced DPP pack. Kernel 104us: pack phase = 32us
//     of STALL (VALUBusy 53%, VGPR_Count=48!). Diagnosis: compiler couldn't
//     keep v[8] (32 VGPRs) live at 48-reg budget -> serialized loads, ~900cy
//     HBM latency exposed at 2 waves/SIMD.
//   r22 (this): same structure + __launch_bounds__(256,2) (VGPR cap 128, no
//     occupancy loss: grid is exactly 2 blk/CU) + explicit ping-pong
//     double-buffer in pack (load chunk i+1 || process chunk i, static
//     buffer names). Predict VGPR ~100+, kernel ~87us, total ~198.

__device__ __forceinline__ uint32_t colfold(uint32_t w) {
    return (w | (w >> 9) | (w >> 18)) & 0x1FFu;
}
__device__ __forceinline__ uint32_t colmaj2(uint32_t w) {   // columns with >=2 bits in band
    return ((w & (w >> 9)) | ((w | (w >> 9)) & (w >> 18))) & 0x1FFu;
}
// quad_perm rotations within the 4-lane quad: band b reads band (b+1)%3 / (b-1)%3.
// ctrl = sel0 | sel1<<2 | sel2<<4 | sel3<<6 : [1,2,0,0]=0x09 ; [2,0,1,0]=0x12
__device__ __forceinline__ uint32_t rotA(uint32_t v) {      // from band+1 (mod 3)
    return (uint32_t)__builtin_amdgcn_update_dpp(0, (int)v, 0x09, 0xF, 0xF, true);
}
__device__ __forceinline__ uint32_t rotB(uint32_t v) {      // from band-1 (mod 3)
    return (uint32_t)__builtin_amdgcn_update_dpp(0, (int)v, 0x12, 0xF, 0xF, true);
}
// pack-tree swaps: quad_perm [1,0,3,2]=0xB1 (lane^1), [2,3,0,1]=0x4E (lane^2)
__device__ __forceinline__ uint32_t dppx1(uint32_t v) {
    return (uint32_t)__builtin_amdgcn_update_dpp(0, (int)v, 0xB1, 0xF, 0xF, true);
}
__device__ __forceinline__ uint32_t dppx2(uint32_t v) {
    return (uint32_t)__builtin_amdgcn_update_dpp(0, (int)v, 0x4E, 0xF, 0xF, true);
}

// ---- pack helpers: load one 8-iter chunk / process one chunk (static inline) ----
__device__ __forceinline__ void loadc(uint4 (&buf)[8], const int ii,
                                      const uint4* __restrict__ src, const int tid) {
    #pragma unroll
    for (int j = 0; j < 8; ++j) {
        int vi = (ii * 8 + j) * 256 + tid;
        if (vi > BLK_V4 - 1) vi = BLK_V4 - 1;   // tail clamp (write masked in procc)
        buf[j] = src[vi];
    }
}
__device__ __forceinline__ void procc(const uint4 (&buf)[8], const int ii,
                                      uint16_t* hp, const int tid) {
    #pragma unroll
    for (int j = 0; j < 8; ++j) {
        int it = ii * 8 + j;
        // inputs are exactly 0.0f/1.0f -> bit 23 of the pattern is the flag
        uint32_t n = ((buf[j].x >> 23) & 1u) | ((buf[j].y >> 22) & 2u)
                   | ((buf[j].z >> 21) & 4u) | ((buf[j].w >> 20) & 8u);
        uint32_t b = n | (dppx1(n) << 4);       // byte, valid on even lanes
        uint32_t h = b | (dppx2(b) << 8);       // u16, valid on lane%4==0
        if ((tid & 3) == 0) {
            int D = it * 32 + (tid >> 3);
            if (D < BLK_DW)
                hp[2 * D + ((tid >> 2) & 1)] = (uint16_t)h;
        }
    }
}

__global__ __launch_bounds__(256, 2)
void sudoku_kernel(const uint32_t* __restrict__ in, float* __restrict__ out,
                   float* __restrict__ solved) {
    __shared__ uint32_t pool[BLK_DW + 2];   // 46656 bits (+pad for extract's 64b read)
    const int tid = threadIdx.x;
    const int q = tid >> 2;                 // puzzle slot 0..63
    const int band = tid & 3;               // 0..2 live, 3 idle in solve
    const int P0 = blockIdx.x * PUZ_PER_BLK;

    // ---------------- PACK (fused, coalesced, double-buffered) ----------------
    // iter it: lane loads vec4 index it*256+tid (wave = 256 contiguous floats).
    // Lane l=8k+m holds floats [32D+4m, 32D+4m+4), D = it*32 + tid/8.
    // DPP xor1 -> byte (m even); DPP xor2 -> u16 (m%4==0); lanes m=0/4 write
    // low/high halves of pool[D] via ds_write_b16 (same bank, 2-way free).
    // Ping-pong v0/v1: next chunk's 8 loads issue before current's process,
    // so 8-16 dwordx4 stay in flight (counted-vmcnt pipelining).
    {
        const uint4* src = (const uint4*)in + (size_t)blockIdx.x * BLK_V4;
        uint16_t* hp = (uint16_t*)pool;
        uint4 v0[8], v1[8];
        loadc(v0, 0, src, tid);
        loadc(v1, 1, src, tid);  procc(v0, 0, hp, tid);
        loadc(v0, 2, src, tid);  procc(v1, 1, hp, tid);
        loadc(v1, 3, src, tid);  procc(v0, 2, hp, tid);
        loadc(v0, 4, src, tid);  procc(v1, 3, hp, tid);
        loadc(v1, 5, src, tid);  procc(v0, 4, hp, tid);
                                 procc(v1, 5, hp, tid);
    }
    __syncthreads();

    // ---- extract 9 band-words for this lane (band 3 reads in-bounds garbage)
    uint32_t bd[9];
    {
        const int bb0 = q * 729 + band * 27;
        #pragma unroll
        for (int d = 0; d < 9; ++d) {
            int bit = bb0 + d * 81;
            int di = bit >> 5, sh = bit & 31;
            uint64_t both = (uint64_t)pool[di] | ((uint64_t)pool[di + 1] << 32);
            bd[d] = (uint32_t)(both >> sh) & FULL27;
        }
    }
    __syncthreads();    // extraction done before pool reuse for expand

    // ---------------- SOLVE (r16/r20-validated quad-DPP logic, unchanged) ------
    #pragma unroll 1
    for (int pass = 0; pass < NPASS; ++pass) {
        // ---------- filter 'box' (band-local) ----------
        {
            uint32_t on = 0, tw = 0, fo = 0;
            #pragma unroll
            for (int d = 0; d < 9; ++d) {
                uint32_t c = on & bd[d];
                on ^= bd[d]; fo |= tw & c; tw ^= c;
            }
            uint32_t ex1 = on & ~tw & ~fo;
            #pragma unroll
            for (int d = 0; d < 9; ++d) {
                uint32_t s = bd[d] & ex1;
                #pragma unroll
                for (int k = 0; k < 3; ++k) {
                    uint32_t bm = 0x1C0E07u << (3 * k);
                    uint32_t sm = s & bm;
                    uint32_t multi = sm & (sm - 1u);
                    uint32_t keep = (sm == 0u) ? 0xFFFFFFFFu : (~bm | (multi ? 0u : sm));
                    bd[d] &= keep;
                }
            }
        }

        // ---------- pointing 'h' (band-local) ----------
        #pragma unroll
        for (int d = 0; d < 9; ++d) {
            uint32_t w = bd[d];
            uint32_t t = (w | (w >> 1) | (w >> 2)) & 0x01249249u;
            uint32_t sum = (t & 0x1FFu) + ((t >> 9) & 0x1FFu) + ((t >> 18) & 0x1FFu);
            uint32_t single = sum & ~(sum >> 1) & 0x49u;
            uint32_t point = t & (single * 0x40201u);
            uint32_t clearm = 0;
            #pragma unroll
            for (int r = 0; r < 3; ++r) {
                uint32_t pr = (point >> (9 * r)) & 0x1FFu;
                uint32_t multi = pr & (pr - 1u);
                uint32_t segkeep = multi ? 0u : pr * 7u;
                uint32_t rc = pr ? ((0x1FFu & ~segkeep) << (9 * r)) : 0u;
                clearm |= rc;
            }
            bd[d] = w & ~clearm;
        }

        // ---------- pointing 'v' (cross-band via DPP) ----------
        {
            uint32_t pnt[9];
            #pragma unroll
            for (int d = 0; d < 9; ++d) {
                uint32_t w = bd[d];
                uint32_t qq = colfold(w);
                uint32_t u = (qq & 0x49u) + ((qq >> 1) & 0x49u) + ((qq >> 2) & 0x49u);
                uint32_t single = u & ~(u >> 1) & 0x49u;
                pnt[d] = qq & (single * 7u);
            }
            #pragma unroll
            for (int d = 0; d < 9; ++d) {
                uint32_t o = rotA(pnt[d]) | rotB(pnt[d]);
                bd[d] &= ~(o * 0x40201u);
            }
        }

        // ---------- unique 'h' (band-local) ----------
        {
            uint32_t hid[9], has = 0;
            #pragma unroll
            for (int d = 0; d < 9; ++d) {
                uint32_t w = bd[d], h = 0;
                #pragma unroll
                for (int r = 0; r < 3; ++r) {
                    uint32_t x = w & (0x1FFu << (9 * r));
                    h |= (x & (x - 1u)) ? 0u : x;
                }
                hid[d] = h; has |= h;
            }
            #pragma unroll
            for (int d = 0; d < 9; ++d) bd[d] = (bd[d] & ~has) | hid[d];
        }

        // ---------- unique 'v' (cross-band via DPP) ----------
        {
            uint32_t hid[9], has = 0;
            #pragma unroll
            for (int d = 0; d < 9; ++d) {
                uint32_t w = bd[d];
                uint32_t q0 = colfold(w), m0 = colmaj2(w);
                uint32_t ex = q0 | (m0 << 9);
                uint32_t ea = rotA(ex);
                uint32_t eb = rotB(ex);
                uint32_t qa = ea & 0x1FFu, ma = ea >> 9;
                uint32_t qb = eb & 0x1FFu, mb = eb >> 9;
                uint32_t ge2 = m0 | ma | mb | (q0 & qa) | (q0 & qb) | (qa & qb);
                uint32_t ex1c = (q0 | qa | qb) & ~ge2;   // column total count == 1
                hid[d] = w & ((ex1c & q0) * 0x40201u);
                has |= hid[d];
            }
            #pragma unroll
            for (int d = 0; d < 9; ++d) bd[d] = (bd[d] & ~has) | hid[d];
        }

        // ---------- unique 'box' (band-local) ----------
        {
            uint32_t hid[9], has = 0;
            #pragma unroll
            for (int d = 0; d < 9; ++d) {
                uint32_t w = bd[d], h = 0;
                #pragma unroll
                for (int k = 0; k < 3; ++k) {
                    uint32_t x = w & (0x1C0E07u << (3 * k));
                    h |= (x & (x - 1u)) ? 0u : x;
                }
                hid[d] = h; has |= h;
            }
            #pragma unroll
            for (int d = 0; d < 9; ++d) bd[d] = (bd[d] & ~has) | hid[d];
        }

        // ---------- doubles 'v' twice (cross-band via DPP) ----------
        #pragma unroll 1
        for (int rep = 0; rep < 2; ++rep) {
            uint32_t on = 0, tw = 0, fo = 0;
            #pragma unroll
            for (int d = 0; d < 9; ++d) {
                uint32_t c = on & bd[d];
                on ^= bd[d]; fo |= tw & c; tw ^= c;
            }
            uint32_t ex2 = tw & ~on & ~fo;
            uint32_t Q[9], K[9];
            #pragma unroll
            for (int d = 0; d < 9; ++d) { Q[d] = bd[d] & ex2; K[d] = 0u; }
            #pragma unroll
            for (int d1 = 0; d1 < 9; ++d1)
                #pragma unroll
                for (int d2 = d1 + 1; d2 < 9; ++d2) {
                    uint32_t P = Q[d1] & Q[d2];
                    uint32_t f0 = colfold(P), g0 = colmaj2(P);
                    uint32_t ex = f0 | (g0 << 9);
                    uint32_t ea = rotA(ex);
                    uint32_t eb = rotB(ex);
                    uint32_t fa = ea & 0x1FFu, ga = ea >> 9;
                    uint32_t fb = eb & 0x1FFu, gb = eb >> 9;
                    // columns with >=2 exact-pair cells across the full column
                    uint32_t dup = g0 | ga | gb | (f0 & fa) | (f0 & fb) | (fa & fb);
                    uint32_t sK = P & (dup * 0x40201u);
                    K[d1] |= sK; K[d2] |= sK;
                }
            #pragma unroll
            for (int d = 0; d < 9; ++d) {
                uint32_t kc = colfold(K[d]);
                uint32_t cols = kc | rotA(kc) | rotB(kc);
                uint32_t em = cols * 0x40201u;
                bd[d] = (bd[d] & ~em) | K[d];
            }
        }

        // ---------- doubles 'box' (band-local) ----------
        {
            uint32_t on = 0, tw = 0, fo = 0;
            #pragma unroll
            for (int d = 0; d < 9; ++d) {
                uint32_t c = on & bd[d];
                on ^= bd[d]; fo |= tw & c; tw ^= c;
            }
            uint32_t ex2 = tw & ~on & ~fo;
            uint32_t Q[9], K[9];
            #pragma unroll
            for (int d = 0; d < 9; ++d) { Q[d] = bd[d] & ex2; K[d] = 0u; }
            #pragma unroll
            for (int d1 = 0; d1 < 9; ++d1)
                #pragma unroll
                for (int d2 = d1 + 1; d2 < 9; ++d2) {
                    uint32_t P = Q[d1] & Q[d2];
                    #pragma unroll
                    for (int k = 0; k < 3; ++k) {
                        uint32_t m = P & (0x1C0E07u << (3 * k));
                        uint32_t s = (m & (m - 1u)) ? m : 0u;
                        K[d1] |= s; K[d2] |= s;
                    }
                }
            #pragma unroll
            for (int d = 0; d < 9; ++d)
                #pragma unroll
                for (int k = 0; k < 3; ++k) {
                    uint32_t bm = 0x1C0E07u << (3 * k);
                    uint32_t t = K[d] & bm;
                    uint32_t mask = t ? (~bm | t) : 0xFFFFFFFFu;
                    bd[d] &= mask;
                }
        }
    } // passes

    // ---------------- solved flag (AND across quad via DPP) ----------------
    {
        uint32_t on = 0, tw = 0, fo = 0;
        #pragma unroll
        for (int d = 0; d < 9; ++d) {
            uint32_t c = on & bd[d];
            on ^= bd[d]; fo |= tw & c; tw ^= c;
        }
        uint32_t okb = ((on & ~tw & ~fo) == FULL27) ? 1u : 0u;
        uint32_t all = okb & rotA(okb) & rotB(okb);
        if (band == 0) solved[P0 + q] = all ? 1.0f : 0.0f;
    }

    // ---------------- EXPAND: repack to pool bitstream -> float4 stores --------
    for (int j = tid; j < BLK_DW + 2; j += 256) pool[j] = 0u;
    __syncthreads();
    if (band != 3) {
        const int pbit = q * 729;
        #pragma unroll
        for (int d = 0; d < 9; ++d) {
            int bitbase = pbit + d * 81 + band * 27;
            int di = bitbase >> 5;
            int sh = bitbase & 31;
            uint64_t both = (uint64_t)bd[d] << sh;
            atomicOr(&pool[di], (uint32_t)both);
            atomicOr(&pool[di + 1], (uint32_t)(both >> 32));
        }
    }
    __syncthreads();
    {
        float4* dst4 = (float4*)(out + (size_t)P0 * 729);  // 46656*blk floats: aligned
        #pragma unroll 4
        for (int i = 0; i < 46; ++i) {                     // 11664 float4s / 256 lanes
            int j = i * 256 + tid;
            if (j < 11664) {
                uint32_t nib = (pool[j >> 3] >> ((j & 7) * 4)) & 0xFu;
                dst4[j] = make_float4((float)(nib & 1u), (float)((nib >> 1) & 1u),
                                      (float)((nib >> 2) & 1u), (float)((nib >> 3) & 1u));
            }
        }
    }
}

extern "C" void kernel_launch(void* const* d_in, const int* in_sizes, int n_in,
                              void* d_out, int out_size, void* d_ws, size_t ws_size,
                              hipStream_t stream) {
    const uint32_t* in = (const uint32_t*)d_in[0];   // float32 bits; 0.0f / 1.0f
    float* out = (float*)d_out;
    float* solved = out + (size_t)NB * 729;
    // single kernel: 512 blocks x 256 threads (2 blocks/CU, 8 waves/CU)
    sudoku_kernel<<<SOLVE_BLKS, 256, 0, stream>>>(in, out, solved);
}

// Round 8
// 207.237 us; speedup vs baseline: 1.1656x; 1.0117x over previous
//
#include <hip/hip_runtime.h>
#include <stdint.h>

#define NB 32768
#define NPASS 4
#define FULL27 0x07FFFFFFu
#define PUZ_PER_BLK 64            // 64 puzzles/block (16 per wave, 4 lanes each)
#define SOLVE_BLKS (NB / PUZ_PER_BLK)   // 512 blocks x 256 threads = 2048 waves
#define BLK_DW 1458               // 64*729/32 dwords of bits per block (exact)
#define BLK_V4 11664              // 64*729/4 vec4 loads per block (exact)

// Per-band bitboard: digit d, band b (rows 3b..3b+2), bit (r*9+c).
// BOX k mask within band: 0x1C0E07 << 3k ; COL c: 0x40201 << c ; ROW r: 0x1FF << 9r
// Flat float layout: puzzle p, digit d, band b, cell j == p*729 + d*81 + b*27 + j.
// Pool layout: bit j of block pool == float blk*46656 + j.
//
// SESSION LEDGER:
//   r15 (216.5us): 3 lanes/puzzle single kernel, ds_bpermute. kernel 107us.
//   r16 (213.5us): quad DPP bands. LDS_CONF 3.0M->192K, VALUBusy 42->55.
//   r17 (241.6us REGRESSION): solve at 512 waves -> half the SIMDs empty.
//   r18/r20 (216.2us): split. Solve 72us @ VALUBusy 73-75%. Pack+gap ~34us
//     (private-chunk line inflation).
//   r21 (215.6us): fused coalesced DPP pack. Kernel 104us; pack = 32us stall,
//     VGPR_Count=48 -> loads serialized, 1 outstanding/wave (~3.1 TB/s eff).
//   r22 (209.7us): +launch_bounds(256,2) + source-level ping-pong. VGPR STILL
//     48, kernel 101.6: launch_bounds caps but doesn't force liveness; the
//     scheduler collapsed the double-buffer. Theory (1-outstanding) intact.
//   r23 (this): pin the ping-pong with sched_barrier(0) fences so loads of
//     chunk i+1 MUST be issued before procc(chunk i) (forces vmcnt(8) waits,
//     8-16 loads in flight). Predict VGPR ~80-110, kernel ~87us, total ~195.

__device__ __forceinline__ uint32_t colfold(uint32_t w) {
    return (w | (w >> 9) | (w >> 18)) & 0x1FFu;
}
__device__ __forceinline__ uint32_t colmaj2(uint32_t w) {   // columns with >=2 bits in band
    return ((w & (w >> 9)) | ((w | (w >> 9)) & (w >> 18))) & 0x1FFu;
}
// quad_perm rotations within the 4-lane quad: band b reads band (b+1)%3 / (b-1)%3.
// ctrl = sel0 | sel1<<2 | sel2<<4 | sel3<<6 : [1,2,0,0]=0x09 ; [2,0,1,0]=0x12
__device__ __forceinline__ uint32_t rotA(uint32_t v) {      // from band+1 (mod 3)
    return (uint32_t)__builtin_amdgcn_update_dpp(0, (int)v, 0x09, 0xF, 0xF, true);
}
__device__ __forceinline__ uint32_t rotB(uint32_t v) {      // from band-1 (mod 3)
    return (uint32_t)__builtin_amdgcn_update_dpp(0, (int)v, 0x12, 0xF, 0xF, true);
}
// pack-tree swaps: quad_perm [1,0,3,2]=0xB1 (lane^1), [2,3,0,1]=0x4E (lane^2)
__device__ __forceinline__ uint32_t dppx1(uint32_t v) {
    return (uint32_t)__builtin_amdgcn_update_dpp(0, (int)v, 0xB1, 0xF, 0xF, true);
}
__device__ __forceinline__ uint32_t dppx2(uint32_t v) {
    return (uint32_t)__builtin_amdgcn_update_dpp(0, (int)v, 0x4E, 0xF, 0xF, true);
}
#define SB() __builtin_amdgcn_sched_barrier(0)

// ---- pack helpers: load one 8-iter chunk / process one chunk (static inline) ----
__device__ __forceinline__ void loadc(uint4 (&buf)[8], const int ii,
                                      const uint4* __restrict__ src, const int tid) {
    #pragma unroll
    for (int j = 0; j < 8; ++j) {
        int vi = (ii * 8 + j) * 256 + tid;
        if (vi > BLK_V4 - 1) vi = BLK_V4 - 1;   // tail clamp (write masked in procc)
        buf[j] = src[vi];
    }
}
__device__ __forceinline__ void procc(const uint4 (&buf)[8], const int ii,
                                      uint16_t* hp, const int tid) {
    #pragma unroll
    for (int j = 0; j < 8; ++j) {
        int it = ii * 8 + j;
        // inputs are exactly 0.0f/1.0f -> bit 23 of the pattern is the flag
        uint32_t n = ((buf[j].x >> 23) & 1u) | ((buf[j].y >> 22) & 2u)
                   | ((buf[j].z >> 21) & 4u) | ((buf[j].w >> 20) & 8u);
        uint32_t b = n | (dppx1(n) << 4);       // byte, valid on even lanes
        uint32_t h = b | (dppx2(b) << 8);       // u16, valid on lane%4==0
        if ((tid & 3) == 0) {
            int D = it * 32 + (tid >> 3);
            if (D < BLK_DW)
                hp[2 * D + ((tid >> 2) & 1)] = (uint16_t)h;
        }
    }
}

__global__ __launch_bounds__(256, 2)
void sudoku_kernel(const uint32_t* __restrict__ in, float* __restrict__ out,
                   float* __restrict__ solved) {
    __shared__ uint32_t pool[BLK_DW + 2];   // 46656 bits (+pad for extract's 64b read)
    const int tid = threadIdx.x;
    const int q = tid >> 2;                 // puzzle slot 0..63
    const int band = tid & 3;               // 0..2 live, 3 idle in solve
    const int P0 = blockIdx.x * PUZ_PER_BLK;

    // ---------------- PACK (fused, coalesced, sched_barrier-pinned dbuf) ------
    // iter it: lane loads vec4 index it*256+tid (wave = 4KB contiguous).
    // Lane l=8k+m holds floats [32D+4m, 32D+4m+4), D = it*32 + tid/8.
    // DPP xor1 -> byte (m even); DPP xor2 -> u16 (m%4==0); lanes m=0/4 write
    // low/high halves of pool[D] via ds_write_b16.
    // sched_barrier(0) fences pin: loads(i+1) issue BEFORE procc(i) -> compiler
    // must emit vmcnt(8), keeping 8-16 dwordx4/wave in flight (r21/r22 showed
    // the scheduler otherwise collapses this to 1 outstanding).
    {
        const uint4* src = (const uint4*)in + (size_t)blockIdx.x * BLK_V4;
        uint16_t* hp = (uint16_t*)pool;
        uint4 v0[8], v1[8];
        loadc(v0, 0, src, tid);                     SB();
        loadc(v1, 1, src, tid);                     SB();
        procc(v0, 0, hp, tid);                      SB();
        loadc(v0, 2, src, tid);                     SB();
        procc(v1, 1, hp, tid);                      SB();
        loadc(v1, 3, src, tid);                     SB();
        procc(v0, 2, hp, tid);                      SB();
        loadc(v0, 4, src, tid);                     SB();
        procc(v1, 3, hp, tid);                      SB();
        loadc(v1, 5, src, tid);                     SB();
        procc(v0, 4, hp, tid);                      SB();
        procc(v1, 5, hp, tid);
    }
    __syncthreads();

    // ---- extract 9 band-words for this lane (band 3 reads in-bounds garbage)
    uint32_t bd[9];
    {
        const int bb0 = q * 729 + band * 27;
        #pragma unroll
        for (int d = 0; d < 9; ++d) {
            int bit = bb0 + d * 81;
            int di = bit >> 5, sh = bit & 31;
            uint64_t both = (uint64_t)pool[di] | ((uint64_t)pool[di + 1] << 32);
            bd[d] = (uint32_t)(both >> sh) & FULL27;
        }
    }
    __syncthreads();    // extraction done before pool reuse for expand

    // ---------------- SOLVE (r16/r20-validated quad-DPP logic, unchanged) ------
    #pragma unroll 1
    for (int pass = 0; pass < NPASS; ++pass) {
        // ---------- filter 'box' (band-local) ----------
        {
            uint32_t on = 0, tw = 0, fo = 0;
            #pragma unroll
            for (int d = 0; d < 9; ++d) {
                uint32_t c = on & bd[d];
                on ^= bd[d]; fo |= tw & c; tw ^= c;
            }
            uint32_t ex1 = on & ~tw & ~fo;
            #pragma unroll
            for (int d = 0; d < 9; ++d) {
                uint32_t s = bd[d] & ex1;
                #pragma unroll
                for (int k = 0; k < 3; ++k) {
                    uint32_t bm = 0x1C0E07u << (3 * k);
                    uint32_t sm = s & bm;
                    uint32_t multi = sm & (sm - 1u);
                    uint32_t keep = (sm == 0u) ? 0xFFFFFFFFu : (~bm | (multi ? 0u : sm));
                    bd[d] &= keep;
                }
            }
        }

        // ---------- pointing 'h' (band-local) ----------
        #pragma unroll
        for (int d = 0; d < 9; ++d) {
            uint32_t w = bd[d];
            uint32_t t = (w | (w >> 1) | (w >> 2)) & 0x01249249u;
            uint32_t sum = (t & 0x1FFu) + ((t >> 9) & 0x1FFu) + ((t >> 18) & 0x1FFu);
            uint32_t single = sum & ~(sum >> 1) & 0x49u;
            uint32_t point = t & (single * 0x40201u);
            uint32_t clearm = 0;
            #pragma unroll
            for (int r = 0; r < 3; ++r) {
                uint32_t pr = (point >> (9 * r)) & 0x1FFu;
                uint32_t multi = pr & (pr - 1u);
                uint32_t segkeep = multi ? 0u : pr * 7u;
                uint32_t rc = pr ? ((0x1FFu & ~segkeep) << (9 * r)) : 0u;
                clearm |= rc;
            }
            bd[d] = w & ~clearm;
        }

        // ---------- pointing 'v' (cross-band via DPP) ----------
        {
            uint32_t pnt[9];
            #pragma unroll
            for (int d = 0; d < 9; ++d) {
                uint32_t w = bd[d];
                uint32_t qq = colfold(w);
                uint32_t u = (qq & 0x49u) + ((qq >> 1) & 0x49u) + ((qq >> 2) & 0x49u);
                uint32_t single = u & ~(u >> 1) & 0x49u;
                pnt[d] = qq & (single * 7u);
            }
            #pragma unroll
            for (int d = 0; d < 9; ++d) {
                uint32_t o = rotA(pnt[d]) | rotB(pnt[d]);
                bd[d] &= ~(o * 0x40201u);
            }
        }

        // ---------- unique 'h' (band-local) ----------
        {
            uint32_t hid[9], has = 0;
            #pragma unroll
            for (int d = 0; d < 9; ++d) {
                uint32_t w = bd[d], h = 0;
                #pragma unroll
                for (int r = 0; r < 3; ++r) {
                    uint32_t x = w & (0x1FFu << (9 * r));
                    h |= (x & (x - 1u)) ? 0u : x;
                }
                hid[d] = h; has |= h;
            }
            #pragma unroll
            for (int d = 0; d < 9; ++d) bd[d] = (bd[d] & ~has) | hid[d];
        }

        // ---------- unique 'v' (cross-band via DPP) ----------
        {
            uint32_t hid[9], has = 0;
            #pragma unroll
            for (int d = 0; d < 9; ++d) {
                uint32_t w = bd[d];
                uint32_t q0 = colfold(w), m0 = colmaj2(w);
                uint32_t ex = q0 | (m0 << 9);
                uint32_t ea = rotA(ex);
                uint32_t eb = rotB(ex);
                uint32_t qa = ea & 0x1FFu, ma = ea >> 9;
                uint32_t qb = eb & 0x1FFu, mb = eb >> 9;
                uint32_t ge2 = m0 | ma | mb | (q0 & qa) | (q0 & qb) | (qa & qb);
                uint32_t ex1c = (q0 | qa | qb) & ~ge2;   // column total count == 1
                hid[d] = w & ((ex1c & q0) * 0x40201u);
                has |= hid[d];
            }
            #pragma unroll
            for (int d = 0; d < 9; ++d) bd[d] = (bd[d] & ~has) | hid[d];
        }

        // ---------- unique 'box' (band-local) ----------
        {
            uint32_t hid[9], has = 0;
            #pragma unroll
            for (int d = 0; d < 9; ++d) {
                uint32_t w = bd[d], h = 0;
                #pragma unroll
                for (int k = 0; k < 3; ++k) {
                    uint32_t x = w & (0x1C0E07u << (3 * k));
                    h |= (x & (x - 1u)) ? 0u : x;
                }
                hid[d] = h; has |= h;
            }
            #pragma unroll
            for (int d = 0; d < 9; ++d) bd[d] = (bd[d] & ~has) | hid[d];
        }

        // ---------- doubles 'v' twice (cross-band via DPP) ----------
        #pragma unroll 1
        for (int rep = 0; rep < 2; ++rep) {
            uint32_t on = 0, tw = 0, fo = 0;
            #pragma unroll
            for (int d = 0; d < 9; ++d) {
                uint32_t c = on & bd[d];
                on ^= bd[d]; fo |= tw & c; tw ^= c;
            }
            uint32_t ex2 = tw & ~on & ~fo;
            uint32_t Q[9], K[9];
            #pragma unroll
            for (int d = 0; d < 9; ++d) { Q[d] = bd[d] & ex2; K[d] = 0u; }
            #pragma unroll
            for (int d1 = 0; d1 < 9; ++d1)
                #pragma unroll
                for (int d2 = d1 + 1; d2 < 9; ++d2) {
                    uint32_t P = Q[d1] & Q[d2];
                    uint32_t f0 = colfold(P), g0 = colmaj2(P);
                    uint32_t ex = f0 | (g0 << 9);
                    uint32_t ea = rotA(ex);
                    uint32_t eb = rotB(ex);
                    uint32_t fa = ea & 0x1FFu, ga = ea >> 9;
                    uint32_t fb = eb & 0x1FFu, gb = eb >> 9;
                    // columns with >=2 exact-pair cells across the full column
                    uint32_t dup = g0 | ga | gb | (f0 & fa) | (f0 & fb) | (fa & fb);
                    uint32_t sK = P & (dup * 0x40201u);
                    K[d1] |= sK; K[d2] |= sK;
                }
            #pragma unroll
            for (int d = 0; d < 9; ++d) {
                uint32_t kc = colfold(K[d]);
                uint32_t cols = kc | rotA(kc) | rotB(kc);
                uint32_t em = cols * 0x40201u;
                bd[d] = (bd[d] & ~em) | K[d];
            }
        }

        // ---------- doubles 'box' (band-local) ----------
        {
            uint32_t on = 0, tw = 0, fo = 0;
            #pragma unroll
            for (int d = 0; d < 9; ++d) {
                uint32_t c = on & bd[d];
                on ^= bd[d]; fo |= tw & c; tw ^= c;
            }
            uint32_t ex2 = tw & ~on & ~fo;
            uint32_t Q[9], K[9];
            #pragma unroll
            for (int d = 0; d < 9; ++d) { Q[d] = bd[d] & ex2; K[d] = 0u; }
            #pragma unroll
            for (int d1 = 0; d1 < 9; ++d1)
                #pragma unroll
                for (int d2 = d1 + 1; d2 < 9; ++d2) {
                    uint32_t P = Q[d1] & Q[d2];
                    #pragma unroll
                    for (int k = 0; k < 3; ++k) {
                        uint32_t m = P & (0x1C0E07u << (3 * k));
                        uint32_t s = (m & (m - 1u)) ? m : 0u;
                        K[d1] |= s; K[d2] |= s;
                    }
                }
            #pragma unroll
            for (int d = 0; d < 9; ++d)
                #pragma unroll
                for (int k = 0; k < 3; ++k) {
                    uint32_t bm = 0x1C0E07u << (3 * k);
                    uint32_t t = K[d] & bm;
                    uint32_t mask = t ? (~bm | t) : 0xFFFFFFFFu;
                    bd[d] &= mask;
                }
        }
    } // passes

    // ---------------- solved flag (AND across quad via DPP) ----------------
    {
        uint32_t on = 0, tw = 0, fo = 0;
        #pragma unroll
        for (int d = 0; d < 9; ++d) {
            uint32_t c = on & bd[d];
            on ^= bd[d]; fo |= tw & c; tw ^= c;
        }
        uint32_t okb = ((on & ~tw & ~fo) == FULL27) ? 1u : 0u;
        uint32_t all = okb & rotA(okb) & rotB(okb);
        if (band == 0) solved[P0 + q] = all ? 1.0f : 0.0f;
    }

    // ---------------- EXPAND: repack to pool bitstream -> float4 stores --------
    for (int j = tid; j < BLK_DW + 2; j += 256) pool[j] = 0u;
    __syncthreads();
    if (band != 3) {
        const int pbit = q * 729;
        #pragma unroll
        for (int d = 0; d < 9; ++d) {
            int bitbase = pbit + d * 81 + band * 27;
            int di = bitbase >> 5;
            int sh = bitbase & 31;
            uint64_t both = (uint64_t)bd[d] << sh;
            atomicOr(&pool[di], (uint32_t)both);
            atomicOr(&pool[di + 1], (uint32_t)(both >> 32));
        }
    }
    __syncthreads();
    {
        float4* dst4 = (float4*)(out + (size_t)P0 * 729);  // 46656*blk floats: aligned
        #pragma unroll 4
        for (int i = 0; i < 46; ++i) {                     // 11664 float4s / 256 lanes
            int j = i * 256 + tid;
            if (j < 11664) {
                uint32_t nib = (pool[j >> 3] >> ((j & 7) * 4)) & 0xFu;
                dst4[j] = make_float4((float)(nib & 1u), (float)((nib >> 1) & 1u),
                                      (float)((nib >> 2) & 1u), (float)((nib >> 3) & 1u));
            }
        }
    }
}

extern "C" void kernel_launch(void* const* d_in, const int* in_sizes, int n_in,
                              void* d_out, int out_size, void* d_ws, size_t ws_size,
                              hipStream_t stream) {
    const uint32_t* in = (const uint32_t*)d_in[0];   // float32 bits; 0.0f / 1.0f
    float* out = (float*)d_out;
    float* solved = out + (size_t)NB * 729;
    // single kernel: 512 blocks x 256 threads (2 blocks/CU, 8 waves/CU)
    sudoku_kernel<<<SOLVE_BLKS, 256, 0, stream>>>(in, out, solved);
}